// Round 15
// baseline (140.736 us; speedup 1.0000x reference)
//
#include <hip/hip_runtime.h>
#include <math.h>

#define S_LEN 1024
#define D_DIM 64
#define NBH   16

typedef unsigned short ushort_t;
typedef unsigned int uint_t;
typedef __attribute__((ext_vector_type(8))) short short8;   // 8 bf16 (4 VGPRs)
typedef __attribute__((ext_vector_type(4))) short short4v;  // 4 x16b (8 B)
typedef __attribute__((ext_vector_type(4))) float f32x4;
typedef __attribute__((ext_vector_type(2))) _Float16 h2;    // v2f16

__device__ __forceinline__ ushort_t rne_bf16(float x) {
    unsigned u = __float_as_uint(x);
    return (ushort_t)((u + 0x7FFFu + ((u >> 16) & 1u)) >> 16);
}
__device__ __forceinline__ void split1(float x, ushort_t& h, ushort_t& l) {
    h = rne_bf16(x);
    float hf = __uint_as_float((unsigned)h << 16);
    l = rne_bf16(x - hf);
}
__device__ __forceinline__ ushort_t f16bits(float x) {
    _Float16 h = (_Float16)x;                 // RNE
    ushort_t b;
    __builtin_memcpy(&b, &h, 2);
    return b;
}
__device__ __forceinline__ h2 as_h2(uint_t u) {
    h2 r;
    __builtin_memcpy(&r, &u, 4);
    return r;
}
#if __has_builtin(__builtin_amdgcn_fdot2)
#define FDOT2(a, b, c) __builtin_amdgcn_fdot2((a), (b), (c), false)
#else
__device__ __forceinline__ float fdot2_sw(h2 a, h2 b, float c) {
    return fmaf((float)a[0], (float)b[0], fmaf((float)a[1], (float)b[1], c));
}
#define FDOT2(a, b, c) fdot2_sw((a), (b), (c))
#endif

// ------------------------------ Prep ----------------------------------------
// blocks [0,512):    K split -> QK B-frag tiled layout
// blocks [512,768):  V transpose-split -> PV B-frag tiled layout
// blocks [768,1024): mask bit-pack
// block  1024:       pack conv weights to half2 triples (SGPR-friendly)
__global__ __launch_bounds__(256) void prep(
    const float* __restrict__ k, const float* __restrict__ v,
    const int* __restrict__ mask, const float* __restrict__ conv_w,
    ushort_t* __restrict__ khi, ushort_t* __restrict__ klo,
    ushort_t* __restrict__ vhi, ushort_t* __restrict__ vlo,
    unsigned* __restrict__ mw, uint_t* __restrict__ wpk)
{
    __shared__ float Ls[64][65];
    const int tid = threadIdx.x;
    const int bx = blockIdx.x;
    if (bx < 512) {
        const int gid  = bx * 256 + tid;
        const int bh   = gid >> 13;
        const int tile = (gid >> 7) & 63;
        const int ch   = (gid >> 6) & 1;
        const int lane = gid & 63;
        const int quad = lane >> 4, t15 = lane & 15;
        const float* src = k + ((size_t)bh * S_LEN + tile * 16 + t15) * D_DIM
                             + ch * 32 + quad * 8;
        float x[8];
        *(float4*)(x + 0) = *(const float4*)(src);
        *(float4*)(x + 4) = *(const float4*)(src + 4);
        short8 hv, lv;
        #pragma unroll
        for (int i = 0; i < 8; ++i) {
            ushort_t h, l;
            split1(x[i], h, l);
            hv[i] = (short)h; lv[i] = (short)l;
        }
        *(short8*)(khi + (size_t)gid * 8) = hv;
        *(short8*)(klo + (size_t)gid * 8) = lv;
    } else if (bx < 768) {
        const int bi = bx - 512;
        const int tt = bi & 15, bh = bi >> 4;
        const float* vb = v + ((size_t)bh * S_LEN + tt * 64) * D_DIM;
        #pragma unroll
        for (int p = 0; p < 4; ++p) {
            int idx = p * 1024 + tid * 4;
            int r = idx >> 6, c = idx & 63;
            float4 x = *(const float4*)(vb + r * 64 + c);
            Ls[r][c] = x.x; Ls[r][c+1] = x.y; Ls[r][c+2] = x.z; Ls[r][c+3] = x.w;
        }
        __syncthreads();
        const int d = tid >> 2, c0 = (tid & 3) * 16;
        ushort_t hi[16], lo[16];
        #pragma unroll
        for (int j = 0; j < 16; ++j) split1(Ls[c0 + j][d], hi[j], lo[j]);
        const int tb0 = tt * 8 + (c0 >> 3);
        const size_t o0 = (((size_t)bh * 128 + tb0) * 64 + d) * 8;
        const size_t o1 = (((size_t)bh * 128 + tb0 + 1) * 64 + d) * 8;
        *(short8*)(vhi + o0) = *(short8*)(hi);
        *(short8*)(vhi + o1) = *(short8*)(hi + 8);
        *(short8*)(vlo + o0) = *(short8*)(lo);
        *(short8*)(vlo + o1) = *(short8*)(lo + 8);
    } else if (bx < 1024) {
        const int gid = (bx - 768) * 256 + tid;
        const int row = gid >> 5, wd = gid & 31;
        const int4* mp = (const int4*)(mask + (size_t)row * 1024 + wd * 32);
        unsigned bits = 0;
        #pragma unroll
        for (int p = 0; p < 8; ++p) {
            int4 qv = mp[p];
            bits |= (qv.x != 0 ? 1u : 0u) << (p * 4 + 0);
            bits |= (qv.y != 0 ? 1u : 0u) << (p * 4 + 1);
            bits |= (qv.z != 0 ? 1u : 0u) << (p * 4 + 2);
            bits |= (qv.w != 0 ? 1u : 0u) << (p * 4 + 3);
        }
        mw[(size_t)row * 32 + wd] = bits;
    } else {
        if (tid < 12) {                       // (f,r) pairs
            const int f = tid / 3, r = tid % 3;
            const float w0 = conv_w[f * 9 + r * 3 + 0];
            const float w1 = conv_w[f * 9 + r * 3 + 1];
            const float w2 = conv_w[f * 9 + r * 3 + 2];
            const uint_t b0 = f16bits(w0), b1 = f16bits(w1), b2 = f16bits(w2);
            const int base = tid * 3;
            wpk[base + 0] = b0 | (b1 << 16);  // (w0,w1)
            wpk[base + 1] = b2;               // (w2,0)
            wpk[base + 2] = b2 << 16;         // (0,w2)
        }
    }
}

// ---------- K1: dp(f16) = (1/8) Q.K^T, MFMA, coalesced f16 stores ------------
// grid (64 s-tiles, 16 bh), block 256 = 4 waves, no barriers.
__global__ __launch_bounds__(256) void qk_mfma(
    const float* __restrict__ q,
    const ushort_t* __restrict__ khi, const ushort_t* __restrict__ klo,
    ushort_t* __restrict__ dph)
{
    __shared__ float Ls[4][16][68];       // per-wave private
    const int st = blockIdx.x, bh = blockIdx.y;
    const int s0 = st * 16;
    const int tid = threadIdx.x;
    const int wave = tid >> 6, lane = tid & 63;
    const int m = lane & 15, quad = lane >> 4;

    // A fragments: Q rows s0+m, pre-scaled by 1/8, split once per block
    const float* qp = q + ((size_t)bh * S_LEN + s0 + m) * D_DIM + quad * 8;
    float qa[16];
    *(float4*)(qa + 0)  = *(const float4*)(qp + 0);
    *(float4*)(qa + 4)  = *(const float4*)(qp + 4);
    *(float4*)(qa + 8)  = *(const float4*)(qp + 32);
    *(float4*)(qa + 12) = *(const float4*)(qp + 36);
    short8 ahi0, alo0, ahi1, alo1;
    #pragma unroll
    for (int i = 0; i < 8; ++i) {
        ushort_t h, l;
        split1(qa[i] * 0.125f, h, l);      ahi0[i] = (short)h; alo0[i] = (short)l;
        split1(qa[8 + i] * 0.125f, h, l);  ahi1[i] = (short)h; alo1[i] = (short)l;
    }

    ushort_t* dpb = dph + ((size_t)bh * S_LEN + s0) * S_LEN;

    #pragma unroll
    for (int sub = 0; sub < 4; ++sub) {
        #pragma unroll
        for (int tt = 0; tt < 4; ++tt) {
            const int tile = wave * 16 + sub * 4 + tt;
            const size_t kb = (((size_t)bh * 64 + tile) * 128 + lane) * 8;
            short8 bhi0 = *(const short8*)(khi + kb);
            short8 blo0 = *(const short8*)(klo + kb);
            short8 bhi1 = *(const short8*)(khi + kb + 512);
            short8 blo1 = *(const short8*)(klo + kb + 512);
            // two independent 3-chains, merged at write
            f32x4 a0 = {0.f, 0.f, 0.f, 0.f}, a1 = {0.f, 0.f, 0.f, 0.f};
            a0 = __builtin_amdgcn_mfma_f32_16x16x32_bf16(ahi0, bhi0, a0, 0, 0, 0);
            a1 = __builtin_amdgcn_mfma_f32_16x16x32_bf16(ahi1, bhi1, a1, 0, 0, 0);
            a0 = __builtin_amdgcn_mfma_f32_16x16x32_bf16(ahi0, blo0, a0, 0, 0, 0);
            a1 = __builtin_amdgcn_mfma_f32_16x16x32_bf16(ahi1, blo1, a1, 0, 0, 0);
            a0 = __builtin_amdgcn_mfma_f32_16x16x32_bf16(alo0, bhi0, a0, 0, 0, 0);
            a1 = __builtin_amdgcn_mfma_f32_16x16x32_bf16(alo1, bhi1, a1, 0, 0, 0);
            #pragma unroll
            for (int r = 0; r < 4; ++r)
                Ls[wave][quad * 4 + r][tt * 16 + m] = a0[r] + a1[r];
        }
        // wave-private transpose readback -> f16, coalesced 128B-run stores
        const int cb = wave * 256 + sub * 64;
        #pragma unroll
        for (int p = 0; p < 4; ++p) {
            const int row = p * 4 + (lane >> 4);
            const int f4  = lane & 15;
            float4 val = *(const float4*)&Ls[wave][row][f4 * 4];
            short4v hv = {(short)f16bits(val.x), (short)f16bits(val.y),
                          (short)f16bits(val.z), (short)f16bits(val.w)};
            *(short4v*)&dpb[(size_t)row * S_LEN + cb + f4 * 4] = hv;
        }
    }
}

// ---------- K2: f16-dot2 conv+leaky+linear+mask+exp -> PV MFMA ---------------
// grid (64 s-tiles, 16 bh), block 512 = 8 waves. LDS ~40 KB -> 4 blocks/CU.
// Conv: thread (rh=tid>>8, cg=tid&255) -> rows rh*8..+7, cols cg*4..+3.
// dp is fp16; per row, 5 packed half2 pairs (via perm/alignbit) feed
// v_dot2_f32_f16 MACs (24/pixel). Weights come pre-packed (uniform scalars).
// P = unnormalized exp bf16 in LDS; PV: wave w -> d0=(w&3)*16, t-half w>>2.
#define PSTR 1048   // pP row stride in ushorts
__global__ __launch_bounds__(512) void conv_av(
    const ushort_t* __restrict__ dph, const unsigned* __restrict__ mw,
    const uint_t* __restrict__ wpk,
    const ushort_t* __restrict__ vhi, const ushort_t* __restrict__ vlo,
    const float* __restrict__ conv_b,
    const float* __restrict__ lin_w, const float* __restrict__ lin_b,
    float* __restrict__ out)
{
    __shared__ ushort_t pP[16 * PSTR];     // 33.5 KB
    __shared__ float oBuf[16][68];         // 4.4 KB
    __shared__ float lsPart[16][4];
    __shared__ unsigned mb[16][32];        // 2 KB

    const int st = blockIdx.x, bh = blockIdx.y;
    const int s0 = st * 16;
    const int b  = bh >> 3;
    const int tid = threadIdx.x;
    const int wave = tid >> 6, lane = tid & 63;
    const int m = lane & 15, quad = lane >> 4;

    {
        const int row = tid >> 5, wd = tid & 31;
        mb[row][wd] = mw[((size_t)b * S_LEN + s0 + row) * 32 + wd];
    }

    float cb[4], lw[4];
    #pragma unroll
    for (int f = 0; f < 4; ++f) { cb[f] = conv_b[f]; lw[f] = lin_w[f]; }
    const float lb = lin_b[0];

    const int rh = tid >> 8, cg = tid & 255, c0 = cg * 4;
    const ushort_t* dpb = dph + (size_t)bh * S_LEN * S_LEN;
    __syncthreads();   // mb visible

    #pragma unroll
    for (int pass = 0; pass < 2; ++pass) {
        const int obase = rh * 8 + pass * 4;        // first of 4 output rows
        // pairs per window row: {(h-1,h0),(h0,h1),(h1,h2),(h2,h3),(h3,h4)}
        uint_t rowp[6][5];
        #pragma unroll
        for (int jj = 0; jj < 6; ++jj) {
            const int ir = s0 + obase - 1 + jj;
            if (ir >= 0 && ir < S_LEN) {
                const ushort_t* rp = dpb + (size_t)ir * S_LEN + c0;
                uint2 dd = *(const uint2*)rp;           // (h0,h1),(h2,h3)
                uint_t sm1 = cg        ? (uint_t)rp[-1] : 0u;
                uint_t s4  = (cg < 255) ? (uint_t)rp[4] : 0u;
                rowp[jj][0] = __builtin_amdgcn_perm(dd.x, sm1, 0x05040100);
                rowp[jj][1] = dd.x;
                rowp[jj][2] = __builtin_amdgcn_alignbit(dd.y, dd.x, 16);
                rowp[jj][3] = dd.y;
                rowp[jj][4] = __builtin_amdgcn_perm(s4, dd.y, 0x05040302);
            } else {
                #pragma unroll
                for (int i = 0; i < 5; ++i) rowp[jj][i] = 0u;
            }
        }
        float ls[4];
        #pragma unroll
        for (int jo = 0; jo < 4; ++jo) {
            const int o = obase + jo;
            float pre[4] = {lb, lb, lb, lb};
            #pragma unroll
            for (int f = 0; f < 4; ++f) {
                float cv0 = cb[f], cv1 = cv0, cv2 = cv0, cv3 = cv0;
                #pragma unroll
                for (int r = 0; r < 3; ++r) {
                    const int base = (f * 3 + r) * 3;
                    const h2 w01 = as_h2(wpk[base + 0]);
                    const h2 w20 = as_h2(wpk[base + 1]);
                    const h2 w02 = as_h2(wpk[base + 2]);
                    const uint_t* P = rowp[jo + r];
                    cv0 = FDOT2(w01, as_h2(P[0]), cv0);
                    cv0 = FDOT2(w20, as_h2(P[2]), cv0);
                    cv1 = FDOT2(w01, as_h2(P[1]), cv1);
                    cv1 = FDOT2(w20, as_h2(P[3]), cv1);
                    cv2 = FDOT2(w01, as_h2(P[2]), cv2);
                    cv2 = FDOT2(w20, as_h2(P[4]), cv2);
                    cv3 = FDOT2(w01, as_h2(P[3]), cv3);
                    cv3 = FDOT2(w02, as_h2(P[4]), cv3);
                }
                const float lwf = lw[f];
                pre[0] = fmaf(lwf, fmaxf(cv0, 0.f) + 0.01f * fminf(cv0, 0.f), pre[0]);
                pre[1] = fmaf(lwf, fmaxf(cv1, 0.f) + 0.01f * fminf(cv1, 0.f), pre[1]);
                pre[2] = fmaf(lwf, fmaxf(cv2, 0.f) + 0.01f * fminf(cv2, 0.f), pre[2]);
                pre[3] = fmaf(lwf, fmaxf(cv3, 0.f) + 0.01f * fminf(cv3, 0.f), pre[3]);
            }
            const unsigned word = mb[o][cg >> 3];
            const unsigned nib  = (word >> ((cg & 7) * 4)) & 0xFu;
            #pragma unroll
            for (int i = 0; i < 4; ++i)
                if (!((nib >> i) & 1u)) pre[i] = -1e30f;
            float pv[4];
            #pragma unroll
            for (int i = 0; i < 4; ++i) pv[i] = __expf(pre[i]);
            ls[jo] = (pv[0] + pv[1]) + (pv[2] + pv[3]);
            short4v hv = {(short)rne_bf16(pv[0]), (short)rne_bf16(pv[1]),
                          (short)rne_bf16(pv[2]), (short)rne_bf16(pv[3])};
            *(short4v*)&pP[o * PSTR + c0] = hv;
        }
        #pragma unroll
        for (int jo = 0; jo < 4; ++jo) {
            float t = ls[jo];
            #pragma unroll
            for (int off = 1; off < 64; off <<= 1) t += __shfl_xor(t, off);
            if (lane == 0) lsPart[obase + jo][wave & 3] = t;
        }
    }
    __syncthreads();

    // ---- PV: wave w -> d0=(w&3)*16, t-chunks (w>>2)*16 .. +15 --------------
    const int d0 = (wave & 3) * 16;
    const int th = wave >> 2;
    f32x4 O = {0.f, 0.f, 0.f, 0.f};
    #pragma unroll 4
    for (int i = 0; i < 16; ++i) {
        const int c = th * 16 + i;
        short8 ph = *(const short8*)&pP[m * PSTR + c * 32 + quad * 8];
        const size_t vb = (((size_t)bh * 128 + c * 4 + quad) * 64 + d0 + m) * 8;
        short8 vh = *(const short8*)(vhi + vb);
        short8 vl = *(const short8*)(vlo + vb);
        O = __builtin_amdgcn_mfma_f32_16x16x32_bf16(ph, vh, O, 0, 0, 0);
        O = __builtin_amdgcn_mfma_f32_16x16x32_bf16(ph, vl, O, 0, 0, 0);
    }
    if (wave < 4) {
        #pragma unroll
        for (int r = 0; r < 4; ++r) oBuf[quad * 4 + r][d0 + m] = O[r];
    }
    __syncthreads();
    if (wave >= 4) {
        #pragma unroll
        for (int r = 0; r < 4; ++r) {
            const int br = quad * 4 + r;
            const float lsum = (lsPart[br][0] + lsPart[br][1]) +
                               (lsPart[br][2] + lsPart[br][3]);
            out[((size_t)bh * S_LEN + s0 + br) * D_DIM + d0 + m] =
                (O[r] + oBuf[br][d0 + m]) / lsum;
        }
    }
}

extern "C" void kernel_launch(void* const* d_in, const int* in_sizes, int n_in,
                              void* d_out, int out_size, void* d_ws, size_t ws_size,
                              hipStream_t stream) {
    const float* q      = (const float*)d_in[0];
    const float* k      = (const float*)d_in[1];
    const float* v      = (const float*)d_in[2];
    const int*   mask   = (const int*)d_in[3];
    const float* conv_w = (const float*)d_in[4];
    const float* conv_b = (const float*)d_in[5];
    const float* lin_w  = (const float*)d_in[6];
    const float* lin_b  = (const float*)d_in[7];
    float* out = (float*)d_out;

    char* wsb = (char*)d_ws;
    const size_t MB = 1024 * 1024;
    ushort_t* khi = (ushort_t*)(wsb + 0 * MB);
    ushort_t* klo = (ushort_t*)(wsb + 2 * MB);
    ushort_t* vhi = (ushort_t*)(wsb + 4 * MB);
    ushort_t* vlo = (ushort_t*)(wsb + 6 * MB);
    unsigned* mw  = (unsigned*)(wsb + 8 * MB);
    uint_t*   wpk = (uint_t*)(wsb + 9 * MB);      // 36 dwords
    ushort_t* dph = (ushort_t*)(wsb + 16 * MB);   // 32 MiB fp16 dp

    prep<<<dim3(1025), 256, 0, stream>>>(k, v, mask, conv_w,
                                         khi, klo, vhi, vlo, mw, wpk);
    qk_mfma<<<dim3(64, NBH), 256, 0, stream>>>(q, khi, klo, dph);
    conv_av<<<dim3(64, NBH), 512, 0, stream>>>(
        dph, mw, wpk, vhi, vlo, conv_b, lin_w, lin_b, out);
}

// Round 16
// 135.235 us; speedup vs baseline: 1.0407x; 1.0407x over previous
//
#include <hip/hip_runtime.h>
#include <math.h>

#define S_LEN 1024
#define D_DIM 64
#define NBH   16

typedef unsigned short ushort_t;
typedef __attribute__((ext_vector_type(8))) short short8;   // 8 bf16 (4 VGPRs)
typedef __attribute__((ext_vector_type(4))) short short4v;  // 4 bf16 (8 B)
typedef __attribute__((ext_vector_type(4))) float f32x4;
typedef __attribute__((ext_vector_type(2))) float f32x2;    // lowers to v_pk_fma_f32

__device__ __forceinline__ ushort_t rne_bf16(float x) {
    unsigned u = __float_as_uint(x);
    return (ushort_t)((u + 0x7FFFu + ((u >> 16) & 1u)) >> 16);
}
__device__ __forceinline__ void split1(float x, ushort_t& h, ushort_t& l) {
    h = rne_bf16(x);
    float hf = __uint_as_float((unsigned)h << 16);
    l = rne_bf16(x - hf);
}

// ------------------------------ Prep ----------------------------------------
// blocks [0,512):    K split -> QK B-frag tiled layout (coalesced 16B writes)
// blocks [512,768):  V transpose-split -> PV B-frag tiled layout
// blocks [768,1024): mask bit-pack, thread-per-word
__global__ __launch_bounds__(256) void prep(
    const float* __restrict__ k, const float* __restrict__ v,
    const int* __restrict__ mask,
    ushort_t* __restrict__ khi, ushort_t* __restrict__ klo,
    ushort_t* __restrict__ vhi, ushort_t* __restrict__ vlo,
    unsigned* __restrict__ mw)
{
    __shared__ float Ls[64][65];
    const int tid = threadIdx.x;
    const int bx = blockIdx.x;
    if (bx < 512) {
        const int gid  = bx * 256 + tid;          // 0..131071
        const int bh   = gid >> 13;
        const int tile = (gid >> 7) & 63;
        const int ch   = (gid >> 6) & 1;
        const int lane = gid & 63;
        const int quad = lane >> 4, t15 = lane & 15;
        const float* src = k + ((size_t)bh * S_LEN + tile * 16 + t15) * D_DIM
                             + ch * 32 + quad * 8;
        float x[8];
        *(float4*)(x + 0) = *(const float4*)(src);
        *(float4*)(x + 4) = *(const float4*)(src + 4);
        short8 hv, lv;
        #pragma unroll
        for (int i = 0; i < 8; ++i) {
            ushort_t h, l;
            split1(x[i], h, l);
            hv[i] = (short)h; lv[i] = (short)l;
        }
        *(short8*)(khi + (size_t)gid * 8) = hv;
        *(short8*)(klo + (size_t)gid * 8) = lv;
    } else if (bx < 768) {
        const int bi = bx - 512;
        const int tt = bi & 15, bh = bi >> 4;
        const float* vb = v + ((size_t)bh * S_LEN + tt * 64) * D_DIM;
        #pragma unroll
        for (int p = 0; p < 4; ++p) {
            int idx = p * 1024 + tid * 4;
            int r = idx >> 6, c = idx & 63;
            float4 x = *(const float4*)(vb + r * 64 + c);
            Ls[r][c] = x.x; Ls[r][c+1] = x.y; Ls[r][c+2] = x.z; Ls[r][c+3] = x.w;
        }
        __syncthreads();
        const int d = tid >> 2, c0 = (tid & 3) * 16;
        ushort_t hi[16], lo[16];
        #pragma unroll
        for (int j = 0; j < 16; ++j) split1(Ls[c0 + j][d], hi[j], lo[j]);
        const int tb0 = tt * 8 + (c0 >> 3);
        const size_t o0 = (((size_t)bh * 128 + tb0) * 64 + d) * 8;
        const size_t o1 = (((size_t)bh * 128 + tb0 + 1) * 64 + d) * 8;
        *(short8*)(vhi + o0) = *(short8*)(hi);
        *(short8*)(vhi + o1) = *(short8*)(hi + 8);
        *(short8*)(vlo + o0) = *(short8*)(lo);
        *(short8*)(vlo + o1) = *(short8*)(lo + 8);
    } else {
        const int gid = (bx - 768) * 256 + tid;    // 0..65535
        const int row = gid >> 5, wd = gid & 31;   // row = b*1024+s
        const int4* mp = (const int4*)(mask + (size_t)row * 1024 + wd * 32);
        unsigned bits = 0;
        #pragma unroll
        for (int p = 0; p < 8; ++p) {
            int4 qv = mp[p];
            bits |= (qv.x != 0 ? 1u : 0u) << (p * 4 + 0);
            bits |= (qv.y != 0 ? 1u : 0u) << (p * 4 + 1);
            bits |= (qv.z != 0 ? 1u : 0u) << (p * 4 + 2);
            bits |= (qv.w != 0 ? 1u : 0u) << (p * 4 + 3);
        }
        mw[(size_t)row * 32 + wd] = bits;
    }
}

// ---------- K1: dp = (1/8) Q.K^T with K-register reuse across 4 s-sets -------
// grid (4 strips, 16 sb, 16 bh) = 1024 blocks, 256 thr = 4 waves, 1 barrier.
// Block covers rows s0..s0+63, cols strip*256..+255. Wave w owns 4 K-tiles
// (cols strip*256 + w*64 ..+63), loaded into registers ONCE (64 VGPR) and
// reused for 4 A-sets staged in LDS -> K traffic 256MB -> 64MB total.
__global__ __launch_bounds__(256) void qk_mfma(
    const float* __restrict__ q,
    const ushort_t* __restrict__ khi, const ushort_t* __restrict__ klo,
    float* __restrict__ dp)
{
    __shared__ ushort_t aBuf[4][4][64 * 8];   // [set][type][lane*8], 16 KB
    __shared__ float Ls[4][16][68];           // 17.4 KB, per-wave private
    const int strip = blockIdx.x, sb = blockIdx.y, bh = blockIdx.z;
    const int s0 = sb * 64;
    const int tid = threadIdx.x;
    const int wave = tid >> 6, lane = tid & 63;
    const int m = lane & 15, quad = lane >> 4;

    // wave w loads+splits Q rows s0 + w*16 + m (pre-scaled by 1/8) -> aBuf[w]
    {
        const float* qp = q + ((size_t)bh * S_LEN + s0 + wave * 16 + m) * D_DIM + quad * 8;
        float qa[16];
        *(float4*)(qa + 0)  = *(const float4*)(qp + 0);
        *(float4*)(qa + 4)  = *(const float4*)(qp + 4);
        *(float4*)(qa + 8)  = *(const float4*)(qp + 32);
        *(float4*)(qa + 12) = *(const float4*)(qp + 36);
        short8 h0, l0, h1, l1;
        #pragma unroll
        for (int i = 0; i < 8; ++i) {
            ushort_t h, l;
            split1(qa[i] * 0.125f, h, l);      h0[i] = (short)h; l0[i] = (short)l;
            split1(qa[8 + i] * 0.125f, h, l);  h1[i] = (short)h; l1[i] = (short)l;
        }
        *(short8*)&aBuf[wave][0][lane * 8] = h0;
        *(short8*)&aBuf[wave][1][lane * 8] = h1;
        *(short8*)&aBuf[wave][2][lane * 8] = l0;
        *(short8*)&aBuf[wave][3][lane * 8] = l1;
    }
    __syncthreads();

    // load this wave's 4 K-tiles once (held in registers across all 4 sets)
    short8 KH0[4], KH1[4], KL0[4], KL1[4];
    #pragma unroll
    for (int tt = 0; tt < 4; ++tt) {
        const int tile = strip * 16 + wave * 4 + tt;
        const size_t kb = (((size_t)bh * 64 + tile) * 128 + lane) * 8;
        KH0[tt] = *(const short8*)(khi + kb);
        KH1[tt] = *(const short8*)(khi + kb + 512);
        KL0[tt] = *(const short8*)(klo + kb);
        KL1[tt] = *(const short8*)(klo + kb + 512);
    }

    const int cb = strip * 256 + wave * 64;
    #pragma unroll
    for (int set = 0; set < 4; ++set) {
        short8 ahi0 = *(const short8*)&aBuf[set][0][lane * 8];
        short8 ahi1 = *(const short8*)&aBuf[set][1][lane * 8];
        short8 alo0 = *(const short8*)&aBuf[set][2][lane * 8];
        short8 alo1 = *(const short8*)&aBuf[set][3][lane * 8];
        #pragma unroll
        for (int tt = 0; tt < 4; ++tt) {
            f32x4 a0 = {0.f, 0.f, 0.f, 0.f}, a1 = {0.f, 0.f, 0.f, 0.f};
            a0 = __builtin_amdgcn_mfma_f32_16x16x32_bf16(ahi0, KH0[tt], a0, 0, 0, 0);
            a1 = __builtin_amdgcn_mfma_f32_16x16x32_bf16(ahi1, KH1[tt], a1, 0, 0, 0);
            a0 = __builtin_amdgcn_mfma_f32_16x16x32_bf16(ahi0, KL0[tt], a0, 0, 0, 0);
            a1 = __builtin_amdgcn_mfma_f32_16x16x32_bf16(ahi1, KL1[tt], a1, 0, 0, 0);
            a0 = __builtin_amdgcn_mfma_f32_16x16x32_bf16(alo0, KH0[tt], a0, 0, 0, 0);
            a1 = __builtin_amdgcn_mfma_f32_16x16x32_bf16(alo1, KH1[tt], a1, 0, 0, 0);
            #pragma unroll
            for (int r = 0; r < 4; ++r)
                Ls[wave][quad * 4 + r][tt * 16 + m] = a0[r] + a1[r];
        }
        // wave-private transpose readback -> coalesced 256B-run stores
        float* rowbase = dp + ((size_t)bh * S_LEN + s0 + set * 16) * S_LEN;
        #pragma unroll
        for (int p = 0; p < 4; ++p) {
            const int row = p * 4 + (lane >> 4);
            const int f4  = lane & 15;
            float4 val = *(const float4*)&Ls[wave][row][f4 * 4];
            *(float4*)&rowbase[(size_t)row * S_LEN + cb + f4 * 4] = val;
        }
    }
}

// ---------- K2: conv+leaky+linear+mask+exp -> PV MFMA (R12-proven) -----------
// grid (64 s-tiles, 16 bh), block 512 = 8 waves. LDS ~40 KB.
#define PSTR 1048   // pP row stride in ushorts
__global__ __launch_bounds__(512) void conv_av(
    const float* __restrict__ dp, const unsigned* __restrict__ mw,
    const ushort_t* __restrict__ vhi, const ushort_t* __restrict__ vlo,
    const float* __restrict__ conv_w, const float* __restrict__ conv_b,
    const float* __restrict__ lin_w, const float* __restrict__ lin_b,
    float* __restrict__ out)
{
    __shared__ ushort_t pP[16 * PSTR];     // 33.5 KB
    __shared__ float oBuf[16][68];         // 4.4 KB
    __shared__ float lsPart[16][4];
    __shared__ unsigned mb[16][32];        // 2 KB

    const int st = blockIdx.x, bh = blockIdx.y;
    const int s0 = st * 16;
    const int b  = bh >> 3;
    const int tid = threadIdx.x;
    const int wave = tid >> 6, lane = tid & 63;
    const int m = lane & 15, quad = lane >> 4;

    {
        const int row = tid >> 5, wd = tid & 31;
        mb[row][wd] = mw[((size_t)b * S_LEN + s0 + row) * 32 + wd];
    }

    float w[36];
    #pragma unroll
    for (int i = 0; i < 36; ++i) w[i] = conv_w[i];
    float cb[4], lw[4];
    #pragma unroll
    for (int f = 0; f < 4; ++f) { cb[f] = conv_b[f]; lw[f] = lin_w[f]; }
    const float lb = lin_b[0];

    const int rh = tid >> 8, cg = tid & 255, c0 = cg * 4;
    const float* dpb = dp + (size_t)bh * S_LEN * S_LEN;
    __syncthreads();   // mb visible

    #pragma unroll
    for (int pass = 0; pass < 2; ++pass) {
        const int obase = rh * 8 + pass * 4;        // first of 4 output rows
        float rowv[6][6];
        #pragma unroll
        for (int jj = 0; jj < 6; ++jj) {
            const int ir = s0 + obase - 1 + jj;
            if (ir >= 0 && ir < S_LEN) {
                const float* rp = dpb + (size_t)ir * S_LEN + c0;
                f32x4 md = *(const f32x4*)rp;
                rowv[jj][0] = cg ? rp[-1] : 0.f;
                rowv[jj][1] = md.x; rowv[jj][2] = md.y;
                rowv[jj][3] = md.z; rowv[jj][4] = md.w;
                rowv[jj][5] = (cg < 255) ? rp[4] : 0.f;
            } else {
                #pragma unroll
                for (int i = 0; i < 6; ++i) rowv[jj][i] = 0.f;
            }
        }
        float ls[4];
        #pragma unroll
        for (int jo = 0; jo < 4; ++jo) {
            const int o = obase + jo;
            f32x2 pa = {lb, lb}, pb = {lb, lb};
            #pragma unroll
            for (int f = 0; f < 4; ++f) {
                f32x2 ca = {cb[f], cb[f]}, cbv = ca;
                #pragma unroll
                for (int dr = 0; dr < 3; ++dr) {
                    const float* vv = rowv[jo + dr];
                    #pragma unroll
                    for (int dc = 0; dc < 3; ++dc) {
                        const float wt = w[f * 9 + dr * 3 + dc];
                        f32x2 ia = {vv[dc],     vv[dc + 1]};
                        f32x2 ib = {vv[dc + 2], vv[dc + 3]};
                        ca  += wt * ia;
                        cbv += wt * ib;
                    }
                }
                f32x2 la  = {fmaxf(ca.x, 0.f)  + 0.01f * fminf(ca.x, 0.f),
                             fmaxf(ca.y, 0.f)  + 0.01f * fminf(ca.y, 0.f)};
                f32x2 lb2 = {fmaxf(cbv.x, 0.f) + 0.01f * fminf(cbv.x, 0.f),
                             fmaxf(cbv.y, 0.f) + 0.01f * fminf(cbv.y, 0.f)};
                pa += lw[f] * la;
                pb += lw[f] * lb2;
            }
            const unsigned word = mb[o][cg >> 3];
            const unsigned nib  = (word >> ((cg & 7) * 4)) & 0xFu;
            float pre[4] = {pa.x, pa.y, pb.x, pb.y};
            #pragma unroll
            for (int i = 0; i < 4; ++i)
                if (!((nib >> i) & 1u)) pre[i] = -1e30f;
            float pv[4];
            #pragma unroll
            for (int i = 0; i < 4; ++i) pv[i] = __expf(pre[i]);
            ls[jo] = (pv[0] + pv[1]) + (pv[2] + pv[3]);
            short4v hv = {(short)rne_bf16(pv[0]), (short)rne_bf16(pv[1]),
                          (short)rne_bf16(pv[2]), (short)rne_bf16(pv[3])};
            *(short4v*)&pP[o * PSTR + c0] = hv;
        }
        #pragma unroll
        for (int jo = 0; jo < 4; ++jo) {
            float t = ls[jo];
            #pragma unroll
            for (int off = 1; off < 64; off <<= 1) t += __shfl_xor(t, off);
            if (lane == 0) lsPart[obase + jo][wave & 3] = t;
        }
    }
    __syncthreads();

    // ---- PV: wave w -> d0=(w&3)*16, t-chunks (w>>2)*16 .. +15 --------------
    const int d0 = (wave & 3) * 16;
    const int th = wave >> 2;
    f32x4 O = {0.f, 0.f, 0.f, 0.f};
    #pragma unroll 4
    for (int i = 0; i < 16; ++i) {
        const int c = th * 16 + i;
        short8 ph = *(const short8*)&pP[m * PSTR + c * 32 + quad * 8];
        const size_t vb = (((size_t)bh * 128 + c * 4 + quad) * 64 + d0 + m) * 8;
        short8 vh = *(const short8*)(vhi + vb);
        short8 vl = *(const short8*)(vlo + vb);
        O = __builtin_amdgcn_mfma_f32_16x16x32_bf16(ph, vh, O, 0, 0, 0);
        O = __builtin_amdgcn_mfma_f32_16x16x32_bf16(ph, vl, O, 0, 0, 0);
    }
    if (wave < 4) {
        #pragma unroll
        for (int r = 0; r < 4; ++r) oBuf[quad * 4 + r][d0 + m] = O[r];
    }
    __syncthreads();
    if (wave >= 4) {
        #pragma unroll
        for (int r = 0; r < 4; ++r) {
            const int br = quad * 4 + r;
            const float lsum = (lsPart[br][0] + lsPart[br][1]) +
                               (lsPart[br][2] + lsPart[br][3]);
            out[((size_t)bh * S_LEN + s0 + br) * D_DIM + d0 + m] =
                (O[r] + oBuf[br][d0 + m]) / lsum;
        }
    }
}

extern "C" void kernel_launch(void* const* d_in, const int* in_sizes, int n_in,
                              void* d_out, int out_size, void* d_ws, size_t ws_size,
                              hipStream_t stream) {
    const float* q      = (const float*)d_in[0];
    const float* k      = (const float*)d_in[1];
    const float* v      = (const float*)d_in[2];
    const int*   mask   = (const int*)d_in[3];
    const float* conv_w = (const float*)d_in[4];
    const float* conv_b = (const float*)d_in[5];
    const float* lin_w  = (const float*)d_in[6];
    const float* lin_b  = (const float*)d_in[7];
    float* out = (float*)d_out;

    char* wsb = (char*)d_ws;
    const size_t MB = 1024 * 1024;
    ushort_t* khi = (ushort_t*)(wsb + 0 * MB);
    ushort_t* klo = (ushort_t*)(wsb + 2 * MB);
    ushort_t* vhi = (ushort_t*)(wsb + 4 * MB);
    ushort_t* vlo = (ushort_t*)(wsb + 6 * MB);
    unsigned* mw  = (unsigned*)(wsb + 8 * MB);
    float*    dp  = (float*)(wsb + 16 * MB);      // 64 MiB

    prep<<<dim3(1024), 256, 0, stream>>>(k, v, mask, khi, klo, vhi, vlo, mw);
    qk_mfma<<<dim3(4, 16, NBH), 256, 0, stream>>>(q, khi, klo, dp);
    conv_av<<<dim3(64, NBH), 512, 0, stream>>>(
        dp, mw, vhi, vlo, conv_w, conv_b, lin_w, lin_b, out);
}

// Round 17
// 131.821 us; speedup vs baseline: 1.0676x; 1.0259x over previous
//
#include <hip/hip_runtime.h>
#include <math.h>

#define S_LEN 1024
#define D_DIM 64
#define NBH   16

typedef unsigned short ushort_t;
typedef unsigned int uint_t;
typedef __attribute__((ext_vector_type(8))) short short8;   // 8 bf16 (4 VGPRs)
typedef __attribute__((ext_vector_type(4))) short short4v;  // 4 x16b (8 B)
typedef __attribute__((ext_vector_type(4))) float f32x4;
typedef __attribute__((ext_vector_type(2))) float f32x2;    // lowers to v_pk_fma_f32
typedef __attribute__((ext_vector_type(2))) _Float16 h2;

__device__ __forceinline__ ushort_t rne_bf16(float x) {
    unsigned u = __float_as_uint(x);
    return (ushort_t)((u + 0x7FFFu + ((u >> 16) & 1u)) >> 16);
}
__device__ __forceinline__ void split1(float x, ushort_t& h, ushort_t& l) {
    h = rne_bf16(x);
    float hf = __uint_as_float((unsigned)h << 16);
    l = rne_bf16(x - hf);
}
__device__ __forceinline__ ushort_t f16bits(float x) {
    _Float16 h = (_Float16)x;                 // RNE
    ushort_t b;
    __builtin_memcpy(&b, &h, 2);
    return b;
}
__device__ __forceinline__ float h2f(ushort_t b) {
    _Float16 h;
    __builtin_memcpy(&h, &b, 2);
    return (float)h;
}
__device__ __forceinline__ h2 as_h2(uint_t u) {
    h2 r;
    __builtin_memcpy(&r, &u, 4);
    return r;
}

// ------------------------------ Prep ----------------------------------------
// blocks [0,512):    K split -> QK B-frag tiled layout (coalesced 16B writes)
// blocks [512,768):  V transpose-split -> PV B-frag tiled layout
// blocks [768,1024): mask bit-pack, thread-per-word
__global__ __launch_bounds__(256) void prep(
    const float* __restrict__ k, const float* __restrict__ v,
    const int* __restrict__ mask,
    ushort_t* __restrict__ khi, ushort_t* __restrict__ klo,
    ushort_t* __restrict__ vhi, ushort_t* __restrict__ vlo,
    unsigned* __restrict__ mw)
{
    __shared__ float Ls[64][65];
    const int tid = threadIdx.x;
    const int bx = blockIdx.x;
    if (bx < 512) {
        const int gid  = bx * 256 + tid;          // 0..131071
        const int bh   = gid >> 13;
        const int tile = (gid >> 7) & 63;
        const int ch   = (gid >> 6) & 1;
        const int lane = gid & 63;
        const int quad = lane >> 4, t15 = lane & 15;
        const float* src = k + ((size_t)bh * S_LEN + tile * 16 + t15) * D_DIM
                             + ch * 32 + quad * 8;
        float x[8];
        *(float4*)(x + 0) = *(const float4*)(src);
        *(float4*)(x + 4) = *(const float4*)(src + 4);
        short8 hv, lv;
        #pragma unroll
        for (int i = 0; i < 8; ++i) {
            ushort_t h, l;
            split1(x[i], h, l);
            hv[i] = (short)h; lv[i] = (short)l;
        }
        *(short8*)(khi + (size_t)gid * 8) = hv;
        *(short8*)(klo + (size_t)gid * 8) = lv;
    } else if (bx < 768) {
        const int bi = bx - 512;
        const int tt = bi & 15, bh = bi >> 4;
        const float* vb = v + ((size_t)bh * S_LEN + tt * 64) * D_DIM;
        #pragma unroll
        for (int p = 0; p < 4; ++p) {
            int idx = p * 1024 + tid * 4;
            int r = idx >> 6, c = idx & 63;
            float4 x = *(const float4*)(vb + r * 64 + c);
            Ls[r][c] = x.x; Ls[r][c+1] = x.y; Ls[r][c+2] = x.z; Ls[r][c+3] = x.w;
        }
        __syncthreads();
        const int d = tid >> 2, c0 = (tid & 3) * 16;
        ushort_t hi[16], lo[16];
        #pragma unroll
        for (int j = 0; j < 16; ++j) split1(Ls[c0 + j][d], hi[j], lo[j]);
        const int tb0 = tt * 8 + (c0 >> 3);
        const size_t o0 = (((size_t)bh * 128 + tb0) * 64 + d) * 8;
        const size_t o1 = (((size_t)bh * 128 + tb0 + 1) * 64 + d) * 8;
        *(short8*)(vhi + o0) = *(short8*)(hi);
        *(short8*)(vhi + o1) = *(short8*)(hi + 8);
        *(short8*)(vlo + o0) = *(short8*)(lo);
        *(short8*)(vlo + o1) = *(short8*)(lo + 8);
    } else {
        const int gid = (bx - 768) * 256 + tid;    // 0..65535
        const int row = gid >> 5, wd = gid & 31;   // row = b*1024+s
        const int4* mp = (const int4*)(mask + (size_t)row * 1024 + wd * 32);
        unsigned bits = 0;
        #pragma unroll
        for (int p = 0; p < 8; ++p) {
            int4 qv = mp[p];
            bits |= (qv.x != 0 ? 1u : 0u) << (p * 4 + 0);
            bits |= (qv.y != 0 ? 1u : 0u) << (p * 4 + 1);
            bits |= (qv.z != 0 ? 1u : 0u) << (p * 4 + 2);
            bits |= (qv.w != 0 ? 1u : 0u) << (p * 4 + 3);
        }
        mw[(size_t)row * 32 + wd] = bits;
    }
}

// ---------- Fused: QK^T (LDS fp16 dp) -> conv+mask+exp -> PV MFMA ------------
// grid (64 s-tiles, 16 bh), block 512 = 8 waves. LDS ~77.6 KB -> 2 blocks/CU.
// Phase A: each wave computes dp rows s0-1..s0+16 for its 128 cols (2 A-sets;
//          set1 contributes only the 2 bottom halo rows) into LDS fp16.
// Phase B: R12-proven conv core (pk-fma) reading dp from LDS; P=exp bf16 LDS.
// Phase C: PV MFMA; 1/rowsum in epilogue.
#define DPSTR 1040  // dp row stride (halfs)
#define PSTR  1048  // pP row stride (halfs)
__global__ __launch_bounds__(512) void fused_qk_conv_av(
    const float* __restrict__ q,
    const ushort_t* __restrict__ khi, const ushort_t* __restrict__ klo,
    const unsigned* __restrict__ mw,
    const ushort_t* __restrict__ vhi, const ushort_t* __restrict__ vlo,
    const float* __restrict__ conv_w, const float* __restrict__ conv_b,
    const float* __restrict__ lin_w, const float* __restrict__ lin_b,
    float* __restrict__ out)
{
    __shared__ ushort_t dpH[18 * DPSTR];   // 37.4 KB fp16 dp rows s0-1..s0+16
    __shared__ ushort_t pP[16 * PSTR];     // 33.5 KB
    __shared__ float oBuf[16][68];         // 4.4 KB
    __shared__ float lsPart[16][4];
    __shared__ unsigned mb[16][32];        // 2 KB

    const int st = blockIdx.x, bh = blockIdx.y;
    const int s0 = st * 16;
    const int b  = bh >> 3;
    const int tid = threadIdx.x;
    const int wave = tid >> 6, lane = tid & 63;
    const int m = lane & 15, quad = lane >> 4;

    // mask bits -> LDS (one word per thread, 512 exactly)
    {
        const int row = tid >> 5, wd = tid & 31;
        mb[row][wd] = mw[((size_t)b * S_LEN + s0 + row) * 32 + wd];
    }

    // ---------------- Phase A: QK into LDS ----------------------------------
    // A-set0: rows s0-1+m (LDS rows 0..15); A-set1: rows s0+1+m (writes LDS 16,17)
    short8 AH0[2], AH1[2], AL0[2], AL1[2];
    #pragma unroll
    for (int set = 0; set < 2; ++set) {
        const int sA = s0 - 1 + 2 * set + m;
        const int sQ = sA < 0 ? 0 : (sA > S_LEN - 1 ? S_LEN - 1 : sA);
        const float* qp = q + ((size_t)bh * S_LEN + sQ) * D_DIM + quad * 8;
        float qa[16];
        *(float4*)(qa + 0)  = *(const float4*)(qp + 0);
        *(float4*)(qa + 4)  = *(const float4*)(qp + 4);
        *(float4*)(qa + 8)  = *(const float4*)(qp + 32);
        *(float4*)(qa + 12) = *(const float4*)(qp + 36);
        #pragma unroll
        for (int i = 0; i < 8; ++i) {
            ushort_t h, l;
            split1(qa[i] * 0.125f, h, l);
            AH0[set][i] = (short)h; AL0[set][i] = (short)l;
            split1(qa[8 + i] * 0.125f, h, l);
            AH1[set][i] = (short)h; AL1[set][i] = (short)l;
        }
    }

    #pragma unroll
    for (int tt = 0; tt < 8; ++tt) {
        const int tile = wave * 8 + tt;
        const size_t kb = (((size_t)bh * 64 + tile) * 128 + lane) * 8;
        short8 KH0 = *(const short8*)(khi + kb);
        short8 KL0 = *(const short8*)(klo + kb);
        short8 KH1 = *(const short8*)(khi + kb + 512);
        short8 KL1 = *(const short8*)(klo + kb + 512);
        const int col = tile * 16 + m;
        {   // set0 -> LDS rows 0..15
            f32x4 a0 = {0.f, 0.f, 0.f, 0.f}, a1 = {0.f, 0.f, 0.f, 0.f};
            a0 = __builtin_amdgcn_mfma_f32_16x16x32_bf16(AH0[0], KH0, a0, 0, 0, 0);
            a1 = __builtin_amdgcn_mfma_f32_16x16x32_bf16(AH1[0], KH1, a1, 0, 0, 0);
            a0 = __builtin_amdgcn_mfma_f32_16x16x32_bf16(AH0[0], KL0, a0, 0, 0, 0);
            a1 = __builtin_amdgcn_mfma_f32_16x16x32_bf16(AH1[0], KL1, a1, 0, 0, 0);
            a0 = __builtin_amdgcn_mfma_f32_16x16x32_bf16(AL0[0], KH0, a0, 0, 0, 0);
            a1 = __builtin_amdgcn_mfma_f32_16x16x32_bf16(AL1[0], KH1, a1, 0, 0, 0);
            #pragma unroll
            for (int r = 0; r < 4; ++r) {
                const int row = quad * 4 + r;
                const int s = s0 - 1 + row;
                const float v = (s >= 0 && s < S_LEN) ? a0[r] + a1[r] : 0.f;
                dpH[row * DPSTR + col] = f16bits(v);
            }
        }
        {   // set1 -> LDS rows 16,17 only (quad==3, r>=2)
            f32x4 a0 = {0.f, 0.f, 0.f, 0.f}, a1 = {0.f, 0.f, 0.f, 0.f};
            a0 = __builtin_amdgcn_mfma_f32_16x16x32_bf16(AH0[1], KH0, a0, 0, 0, 0);
            a1 = __builtin_amdgcn_mfma_f32_16x16x32_bf16(AH1[1], KH1, a1, 0, 0, 0);
            a0 = __builtin_amdgcn_mfma_f32_16x16x32_bf16(AH0[1], KL0, a0, 0, 0, 0);
            a1 = __builtin_amdgcn_mfma_f32_16x16x32_bf16(AH1[1], KL1, a1, 0, 0, 0);
            a0 = __builtin_amdgcn_mfma_f32_16x16x32_bf16(AL0[1], KH0, a0, 0, 0, 0);
            a1 = __builtin_amdgcn_mfma_f32_16x16x32_bf16(AL1[1], KH1, a1, 0, 0, 0);
            if (quad == 3) {
                #pragma unroll
                for (int r = 2; r < 4; ++r) {
                    const int mrow = quad * 4 + r;           // 14,15
                    const int s = s0 + 1 + mrow;             // s0+15, s0+16
                    const float v = (s < S_LEN) ? a0[r] + a1[r] : 0.f;
                    dpH[(mrow + 2) * DPSTR + col] = f16bits(v);
                }
            }
        }
    }

    float w[36];
    #pragma unroll
    for (int i = 0; i < 36; ++i) w[i] = conv_w[i];
    float cb[4], lw[4];
    #pragma unroll
    for (int f = 0; f < 4; ++f) { cb[f] = conv_b[f]; lw[f] = lin_w[f]; }
    const float lb = lin_b[0];

    __syncthreads();

    // ---------------- Phase B: conv + mask + exp -----------------------------
    const int rh = tid >> 8, cg = tid & 255, c0 = cg * 4;
    #pragma unroll
    for (int pass = 0; pass < 2; ++pass) {
        const int obase = rh * 8 + pass * 4;        // first of 4 output rows
        // 6-row window from LDS (conv output row o needs LDS rows o..o+2)
        float rowv[6][6];
        #pragma unroll
        for (int jj = 0; jj < 6; ++jj) {
            const ushort_t* rp = &dpH[(obase + jj) * DPSTR + c0];
            uint2 dd = *(const uint2*)rp;
            h2 p0 = as_h2(dd.x), p1 = as_h2(dd.y);
            rowv[jj][0] = cg ? h2f(rp[-1]) : 0.f;
            rowv[jj][1] = (float)p0[0]; rowv[jj][2] = (float)p0[1];
            rowv[jj][3] = (float)p1[0]; rowv[jj][4] = (float)p1[1];
            rowv[jj][5] = (cg < 255) ? h2f(rp[4]) : 0.f;
        }
        float ls[4];
        #pragma unroll
        for (int jo = 0; jo < 4; ++jo) {
            const int o = obase + jo;
            f32x2 pa = {lb, lb}, pb = {lb, lb};
            #pragma unroll
            for (int f = 0; f < 4; ++f) {
                f32x2 ca = {cb[f], cb[f]}, cbv = ca;
                #pragma unroll
                for (int dr = 0; dr < 3; ++dr) {
                    const float* vv = rowv[jo + dr];
                    #pragma unroll
                    for (int dc = 0; dc < 3; ++dc) {
                        const float wt = w[f * 9 + dr * 3 + dc];
                        f32x2 ia = {vv[dc],     vv[dc + 1]};
                        f32x2 ib = {vv[dc + 2], vv[dc + 3]};
                        ca  += wt * ia;
                        cbv += wt * ib;
                    }
                }
                f32x2 la  = {fmaxf(ca.x, 0.f)  + 0.01f * fminf(ca.x, 0.f),
                             fmaxf(ca.y, 0.f)  + 0.01f * fminf(ca.y, 0.f)};
                f32x2 lb2 = {fmaxf(cbv.x, 0.f) + 0.01f * fminf(cbv.x, 0.f),
                             fmaxf(cbv.y, 0.f) + 0.01f * fminf(cbv.y, 0.f)};
                pa += lw[f] * la;
                pb += lw[f] * lb2;
            }
            const unsigned word = mb[o][cg >> 3];
            const unsigned nib  = (word >> ((cg & 7) * 4)) & 0xFu;
            float pre[4] = {pa.x, pa.y, pb.x, pb.y};
            #pragma unroll
            for (int i = 0; i < 4; ++i)
                if (!((nib >> i) & 1u)) pre[i] = -1e30f;
            float pv[4];
            #pragma unroll
            for (int i = 0; i < 4; ++i) pv[i] = __expf(pre[i]);
            ls[jo] = (pv[0] + pv[1]) + (pv[2] + pv[3]);
            short4v hv = {(short)rne_bf16(pv[0]), (short)rne_bf16(pv[1]),
                          (short)rne_bf16(pv[2]), (short)rne_bf16(pv[3])};
            *(short4v*)&pP[o * PSTR + c0] = hv;
        }
        #pragma unroll
        for (int jo = 0; jo < 4; ++jo) {
            float t = ls[jo];
            #pragma unroll
            for (int off = 1; off < 64; off <<= 1) t += __shfl_xor(t, off);
            if (lane == 0) lsPart[obase + jo][wave & 3] = t;
        }
    }
    __syncthreads();

    // ---------------- Phase C: PV ------------------------------------------
    const int d0 = (wave & 3) * 16;
    const int th = wave >> 2;
    f32x4 O = {0.f, 0.f, 0.f, 0.f};
    #pragma unroll 4
    for (int i = 0; i < 16; ++i) {
        const int c = th * 16 + i;
        short8 ph = *(const short8*)&pP[m * PSTR + c * 32 + quad * 8];
        const size_t vb = (((size_t)bh * 128 + c * 4 + quad) * 64 + d0 + m) * 8;
        short8 vh = *(const short8*)(vhi + vb);
        short8 vl = *(const short8*)(vlo + vb);
        O = __builtin_amdgcn_mfma_f32_16x16x32_bf16(ph, vh, O, 0, 0, 0);
        O = __builtin_amdgcn_mfma_f32_16x16x32_bf16(ph, vl, O, 0, 0, 0);
    }
    if (wave < 4) {
        #pragma unroll
        for (int r = 0; r < 4; ++r) oBuf[quad * 4 + r][d0 + m] = O[r];
    }
    __syncthreads();
    if (wave >= 4) {
        #pragma unroll
        for (int r = 0; r < 4; ++r) {
            const int br = quad * 4 + r;
            const float lsum = (lsPart[br][0] + lsPart[br][1]) +
                               (lsPart[br][2] + lsPart[br][3]);
            out[((size_t)bh * S_LEN + s0 + br) * D_DIM + d0 + m] =
                (O[r] + oBuf[br][d0 + m]) / lsum;
        }
    }
}

extern "C" void kernel_launch(void* const* d_in, const int* in_sizes, int n_in,
                              void* d_out, int out_size, void* d_ws, size_t ws_size,
                              hipStream_t stream) {
    const float* q      = (const float*)d_in[0];
    const float* k      = (const float*)d_in[1];
    const float* v      = (const float*)d_in[2];
    const int*   mask   = (const int*)d_in[3];
    const float* conv_w = (const float*)d_in[4];
    const float* conv_b = (const float*)d_in[5];
    const float* lin_w  = (const float*)d_in[6];
    const float* lin_b  = (const float*)d_in[7];
    float* out = (float*)d_out;

    char* wsb = (char*)d_ws;
    const size_t MB = 1024 * 1024;
    ushort_t* khi = (ushort_t*)(wsb + 0 * MB);
    ushort_t* klo = (ushort_t*)(wsb + 2 * MB);
    ushort_t* vhi = (ushort_t*)(wsb + 4 * MB);
    ushort_t* vlo = (ushort_t*)(wsb + 6 * MB);
    unsigned* mw  = (unsigned*)(wsb + 8 * MB);

    prep<<<dim3(1024), 256, 0, stream>>>(k, v, mask, khi, klo, vhi, vlo, mw);
    fused_qk_conv_av<<<dim3(64, NBH), 512, 0, stream>>>(
        q, khi, klo, mw, vhi, vlo, conv_w, conv_b, lin_w, lin_b, out);
}

// Round 18
// 131.421 us; speedup vs baseline: 1.0709x; 1.0030x over previous
//
#include <hip/hip_runtime.h>
#include <math.h>

#define S_LEN 1024
#define D_DIM 64
#define NBH   16
#define RPB   14
#define NSB   74           // ceil(1024/14)

typedef unsigned short ushort_t;
typedef unsigned int uint_t;
typedef __attribute__((ext_vector_type(8))) short short8;   // 8 bf16 (4 VGPRs)
typedef __attribute__((ext_vector_type(4))) short short4v;  // 4 x16b (8 B)
typedef __attribute__((ext_vector_type(4))) float f32x4;
typedef __attribute__((ext_vector_type(2))) float f32x2;    // lowers to v_pk_fma_f32
typedef __attribute__((ext_vector_type(2))) _Float16 h2;

__device__ __forceinline__ ushort_t rne_bf16(float x) {
    unsigned u = __float_as_uint(x);
    return (ushort_t)((u + 0x7FFFu + ((u >> 16) & 1u)) >> 16);
}
__device__ __forceinline__ void split1(float x, ushort_t& h, ushort_t& l) {
    h = rne_bf16(x);
    float hf = __uint_as_float((unsigned)h << 16);
    l = rne_bf16(x - hf);
}
__device__ __forceinline__ ushort_t f16bits(float x) {
    _Float16 h = (_Float16)x;                 // RNE
    ushort_t b;
    __builtin_memcpy(&b, &h, 2);
    return b;
}
__device__ __forceinline__ float h2f(ushort_t b) {
    _Float16 h;
    __builtin_memcpy(&h, &b, 2);
    return (float)h;
}
__device__ __forceinline__ h2 as_h2(uint_t u) {
    h2 r;
    __builtin_memcpy(&r, &u, 4);
    return r;
}

// ------------------------------ Prep ----------------------------------------
// blocks [0,512):    K split -> QK B-frag tiled layout (coalesced 16B writes)
// blocks [512,768):  V transpose-split -> PV B-frag tiled layout
// blocks [768,1024): mask bit-pack, thread-per-word
__global__ __launch_bounds__(256) void prep(
    const float* __restrict__ k, const float* __restrict__ v,
    const int* __restrict__ mask,
    ushort_t* __restrict__ khi, ushort_t* __restrict__ klo,
    ushort_t* __restrict__ vhi, ushort_t* __restrict__ vlo,
    unsigned* __restrict__ mw)
{
    __shared__ float Ls[64][65];
    const int tid = threadIdx.x;
    const int bx = blockIdx.x;
    if (bx < 512) {
        const int gid  = bx * 256 + tid;          // 0..131071
        const int bh   = gid >> 13;
        const int tile = (gid >> 7) & 63;
        const int ch   = (gid >> 6) & 1;
        const int lane = gid & 63;
        const int quad = lane >> 4, t15 = lane & 15;
        const float* src = k + ((size_t)bh * S_LEN + tile * 16 + t15) * D_DIM
                             + ch * 32 + quad * 8;
        float x[8];
        *(float4*)(x + 0) = *(const float4*)(src);
        *(float4*)(x + 4) = *(const float4*)(src + 4);
        short8 hv, lv;
        #pragma unroll
        for (int i = 0; i < 8; ++i) {
            ushort_t h, l;
            split1(x[i], h, l);
            hv[i] = (short)h; lv[i] = (short)l;
        }
        *(short8*)(khi + (size_t)gid * 8) = hv;
        *(short8*)(klo + (size_t)gid * 8) = lv;
    } else if (bx < 768) {
        const int bi = bx - 512;
        const int tt = bi & 15, bh = bi >> 4;
        const float* vb = v + ((size_t)bh * S_LEN + tt * 64) * D_DIM;
        #pragma unroll
        for (int p = 0; p < 4; ++p) {
            int idx = p * 1024 + tid * 4;
            int r = idx >> 6, c = idx & 63;
            float4 x = *(const float4*)(vb + r * 64 + c);
            Ls[r][c] = x.x; Ls[r][c+1] = x.y; Ls[r][c+2] = x.z; Ls[r][c+3] = x.w;
        }
        __syncthreads();
        const int d = tid >> 2, c0 = (tid & 3) * 16;
        ushort_t hi[16], lo[16];
        #pragma unroll
        for (int j = 0; j < 16; ++j) split1(Ls[c0 + j][d], hi[j], lo[j]);
        const int tb0 = tt * 8 + (c0 >> 3);
        const size_t o0 = (((size_t)bh * 128 + tb0) * 64 + d) * 8;
        const size_t o1 = (((size_t)bh * 128 + tb0 + 1) * 64 + d) * 8;
        *(short8*)(vhi + o0) = *(short8*)(hi);
        *(short8*)(vhi + o1) = *(short8*)(hi + 8);
        *(short8*)(vlo + o0) = *(short8*)(lo);
        *(short8*)(vlo + o1) = *(short8*)(lo + 8);
    } else {
        const int gid = (bx - 768) * 256 + tid;    // 0..65535
        const int row = gid >> 5, wd = gid & 31;   // row = b*1024+s
        const int4* mp = (const int4*)(mask + (size_t)row * 1024 + wd * 32);
        unsigned bits = 0;
        #pragma unroll
        for (int p = 0; p < 8; ++p) {
            int4 qv = mp[p];
            bits |= (qv.x != 0 ? 1u : 0u) << (p * 4 + 0);
            bits |= (qv.y != 0 ? 1u : 0u) << (p * 4 + 1);
            bits |= (qv.z != 0 ? 1u : 0u) << (p * 4 + 2);
            bits |= (qv.w != 0 ? 1u : 0u) << (p * 4 + 3);
        }
        mw[(size_t)row * 32 + wd] = bits;
    }
}

// ---------- Fused (RPB=14): QK^T (LDS fp16) -> conv+mask+exp -> PV MFMA ------
// grid (74 s-tiles, 16 bh), block 512 = 8 waves. LDS ~73.5 KB -> 2 blocks/CU.
// Block outputs rows s0..s0+13 (s0=st*14). ONE 16-row A-set (rows s0-1+m)
// produces exactly the 16 dp rows conv needs (14 payload + 2 halo).
// dpH row dr <-> global s = s0-1+dr. Conv outputs o in 1..14; P rows 0,15 = 0.
#define DPSTR 1040  // dp row stride (halfs)
#define PSTR  1048  // pP row stride (halfs)
__global__ __launch_bounds__(512) void fused_qk_conv_av(
    const float* __restrict__ q,
    const ushort_t* __restrict__ khi, const ushort_t* __restrict__ klo,
    const unsigned* __restrict__ mw,
    const ushort_t* __restrict__ vhi, const ushort_t* __restrict__ vlo,
    const float* __restrict__ conv_w, const float* __restrict__ conv_b,
    const float* __restrict__ lin_w, const float* __restrict__ lin_b,
    float* __restrict__ out)
{
    __shared__ ushort_t dpH[16 * DPSTR];   // 33.3 KB fp16 dp rows s0-1..s0+14
    __shared__ ushort_t pP[16 * PSTR];     // 33.5 KB
    __shared__ float oBuf[16][68];         // 4.4 KB
    __shared__ float lsPart[16][4];
    __shared__ unsigned mb[16][32];        // 2 KB

    const int st = blockIdx.x, bh = blockIdx.y;
    const int s0 = st * RPB;
    const int b  = bh >> 3;
    const int tid = threadIdx.x;
    const int wave = tid >> 6, lane = tid & 63;
    const int m = lane & 15, quad = lane >> 4;

    // mask bits -> LDS (one word per thread; row o <-> s = s0-1+o)
    {
        const int o = tid >> 5, wd = tid & 31;
        const int s = s0 - 1 + o;
        mb[o][wd] = (s >= 0 && s < S_LEN)
                  ? mw[((size_t)b * S_LEN + s) * 32 + wd] : 0u;
    }

    // ---------------- Phase A: QK into LDS (single A-set) -------------------
    const int sA = s0 - 1 + m;
    const int sQ = sA < 0 ? 0 : (sA > S_LEN - 1 ? S_LEN - 1 : sA);
    const float* qp = q + ((size_t)bh * S_LEN + sQ) * D_DIM + quad * 8;
    float qa[16];
    *(float4*)(qa + 0)  = *(const float4*)(qp + 0);
    *(float4*)(qa + 4)  = *(const float4*)(qp + 4);
    *(float4*)(qa + 8)  = *(const float4*)(qp + 32);
    *(float4*)(qa + 12) = *(const float4*)(qp + 36);
    short8 AH0, AH1, AL0, AL1;
    #pragma unroll
    for (int i = 0; i < 8; ++i) {
        ushort_t h, l;
        split1(qa[i] * 0.125f, h, l);      AH0[i] = (short)h; AL0[i] = (short)l;
        split1(qa[8 + i] * 0.125f, h, l);  AH1[i] = (short)h; AL1[i] = (short)l;
    }

    #pragma unroll
    for (int tt = 0; tt < 8; ++tt) {
        const int tile = wave * 8 + tt;
        const size_t kb = (((size_t)bh * 64 + tile) * 128 + lane) * 8;
        short8 KH0 = *(const short8*)(khi + kb);
        short8 KL0 = *(const short8*)(klo + kb);
        short8 KH1 = *(const short8*)(khi + kb + 512);
        short8 KL1 = *(const short8*)(klo + kb + 512);
        f32x4 a0 = {0.f, 0.f, 0.f, 0.f}, a1 = {0.f, 0.f, 0.f, 0.f};
        a0 = __builtin_amdgcn_mfma_f32_16x16x32_bf16(AH0, KH0, a0, 0, 0, 0);
        a1 = __builtin_amdgcn_mfma_f32_16x16x32_bf16(AH1, KH1, a1, 0, 0, 0);
        a0 = __builtin_amdgcn_mfma_f32_16x16x32_bf16(AH0, KL0, a0, 0, 0, 0);
        a1 = __builtin_amdgcn_mfma_f32_16x16x32_bf16(AH1, KL1, a1, 0, 0, 0);
        a0 = __builtin_amdgcn_mfma_f32_16x16x32_bf16(AL0, KH0, a0, 0, 0, 0);
        a1 = __builtin_amdgcn_mfma_f32_16x16x32_bf16(AL1, KH1, a1, 0, 0, 0);
        const int col = tile * 16 + m;
        #pragma unroll
        for (int r = 0; r < 4; ++r) {
            const int row = quad * 4 + r;
            const int s = s0 - 1 + row;
            const float v = (s >= 0 && s < S_LEN) ? a0[r] + a1[r] : 0.f;
            dpH[row * DPSTR + col] = f16bits(v);
        }
    }

    float w[36];
    #pragma unroll
    for (int i = 0; i < 36; ++i) w[i] = conv_w[i];
    float cb[4], lw[4];
    #pragma unroll
    for (int f = 0; f < 4; ++f) { cb[f] = conv_b[f]; lw[f] = lin_w[f]; }
    const float lb = lin_b[0];
    const f32x2 zero2 = {0.f, 0.f};
    const f32x2 c001  = {0.01f, 0.01f};

    __syncthreads();

    // ---------------- Phase B: conv + mask + exp -----------------------------
    const int rh = tid >> 8, cg = tid & 255, c0 = cg * 4;
    #pragma unroll
    for (int pass = 0; pass < 2; ++pass) {
        const int obase = rh * 8 + pass * 4;        // first of 4 output rows
        // 6-row window from LDS (output row o needs dpH rows o-1..o+1)
        float rowv[6][6];
        #pragma unroll
        for (int jj = 0; jj < 6; ++jj) {
            const int dr = obase - 1 + jj;          // -1..16
            if (dr >= 0 && dr < 16) {
                const ushort_t* rp = &dpH[dr * DPSTR + c0];
                uint2 dd = *(const uint2*)rp;
                h2 p0 = as_h2(dd.x), p1 = as_h2(dd.y);
                rowv[jj][0] = cg ? h2f(rp[-1]) : 0.f;
                rowv[jj][1] = (float)p0[0]; rowv[jj][2] = (float)p0[1];
                rowv[jj][3] = (float)p1[0]; rowv[jj][4] = (float)p1[1];
                rowv[jj][5] = (cg < 255) ? h2f(rp[4]) : 0.f;
            } else {
                #pragma unroll
                for (int i = 0; i < 6; ++i) rowv[jj][i] = 0.f;
            }
        }
        float ls[4];
        #pragma unroll
        for (int jo = 0; jo < 4; ++jo) {
            const int o = obase + jo;
            const bool act = (o >= 1) && (o <= RPB) && (s0 - 1 + o < S_LEN);
            if (act) {
                f32x2 pa = {lb, lb}, pb = {lb, lb};
                #pragma unroll
                for (int f = 0; f < 4; ++f) {
                    f32x2 ca = {cb[f], cb[f]}, cbv = ca;
                    #pragma unroll
                    for (int dr = 0; dr < 3; ++dr) {
                        const float* vv = rowv[jo + dr];
                        #pragma unroll
                        for (int dc = 0; dc < 3; ++dc) {
                            const float wt = w[f * 9 + dr * 3 + dc];
                            const f32x2 wt2 = {wt, wt};
                            f32x2 ia = {vv[dc],     vv[dc + 1]};
                            f32x2 ib = {vv[dc + 2], vv[dc + 3]};
                            ca  = __builtin_elementwise_fma(wt2, ia, ca);
                            cbv = __builtin_elementwise_fma(wt2, ib, cbv);
                        }
                    }
                    const f32x2 lwv = {lw[f], lw[f]};
                    f32x2 la  = __builtin_elementwise_fma(
                        c001, __builtin_elementwise_min(ca, zero2),
                        __builtin_elementwise_max(ca, zero2));
                    f32x2 lb2 = __builtin_elementwise_fma(
                        c001, __builtin_elementwise_min(cbv, zero2),
                        __builtin_elementwise_max(cbv, zero2));
                    pa = __builtin_elementwise_fma(lwv, la, pa);
                    pb = __builtin_elementwise_fma(lwv, lb2, pb);
                }
                const unsigned word = mb[o][cg >> 3];
                const unsigned nib  = (word >> ((cg & 7) * 4)) & 0xFu;
                float pre[4] = {pa.x, pa.y, pb.x, pb.y};
                #pragma unroll
                for (int i = 0; i < 4; ++i)
                    if (!((nib >> i) & 1u)) pre[i] = -1e30f;
                float pv[4];
                #pragma unroll
                for (int i = 0; i < 4; ++i) pv[i] = __expf(pre[i]);
                ls[jo] = (pv[0] + pv[1]) + (pv[2] + pv[3]);
                short4v hv = {(short)rne_bf16(pv[0]), (short)rne_bf16(pv[1]),
                              (short)rne_bf16(pv[2]), (short)rne_bf16(pv[3])};
                *(short4v*)&pP[o * PSTR + c0] = hv;
            } else {
                short4v z = {0, 0, 0, 0};
                *(short4v*)&pP[o * PSTR + c0] = z;
                ls[jo] = 0.f;
            }
        }
        #pragma unroll
        for (int jo = 0; jo < 4; ++jo) {
            float t = ls[jo];
            #pragma unroll
            for (int off = 1; off < 64; off <<= 1) t += __shfl_xor(t, off);
            if (lane == 0) lsPart[obase + jo][wave & 3] = t;
        }
    }
    __syncthreads();

    // ---------------- Phase C: PV ------------------------------------------
    const int d0 = (wave & 3) * 16;
    const int th = wave >> 2;
    f32x4 O = {0.f, 0.f, 0.f, 0.f};
    #pragma unroll 4
    for (int i = 0; i < 16; ++i) {
        const int c = th * 16 + i;
        short8 ph = *(const short8*)&pP[m * PSTR + c * 32 + quad * 8];
        const size_t vb = (((size_t)bh * 128 + c * 4 + quad) * 64 + d0 + m) * 8;
        short8 vh = *(const short8*)(vhi + vb);
        short8 vl = *(const short8*)(vlo + vb);
        O = __builtin_amdgcn_mfma_f32_16x16x32_bf16(ph, vh, O, 0, 0, 0);
        O = __builtin_amdgcn_mfma_f32_16x16x32_bf16(ph, vl, O, 0, 0, 0);
    }
    if (wave < 4) {
        #pragma unroll
        for (int r = 0; r < 4; ++r) oBuf[quad * 4 + r][d0 + m] = O[r];
    }
    __syncthreads();
    if (wave >= 4) {
        #pragma unroll
        for (int r = 0; r < 4; ++r) {
            const int br = quad * 4 + r;
            const int s = s0 - 1 + br;
            if (br >= 1 && br <= RPB && s < S_LEN) {
                const float lsum = (lsPart[br][0] + lsPart[br][1]) +
                                   (lsPart[br][2] + lsPart[br][3]);
                out[((size_t)bh * S_LEN + s) * D_DIM + d0 + m] =
                    (O[r] + oBuf[br][d0 + m]) / lsum;
            }
        }
    }
}

extern "C" void kernel_launch(void* const* d_in, const int* in_sizes, int n_in,
                              void* d_out, int out_size, void* d_ws, size_t ws_size,
                              hipStream_t stream) {
    const float* q      = (const float*)d_in[0];
    const float* k      = (const float*)d_in[1];
    const float* v      = (const float*)d_in[2];
    const int*   mask   = (const int*)d_in[3];
    const float* conv_w = (const float*)d_in[4];
    const float* conv_b = (const float*)d_in[5];
    const float* lin_w  = (const float*)d_in[6];
    const float* lin_b  = (const float*)d_in[7];
    float* out = (float*)d_out;

    char* wsb = (char*)d_ws;
    const size_t MB = 1024 * 1024;
    ushort_t* khi = (ushort_t*)(wsb + 0 * MB);
    ushort_t* klo = (ushort_t*)(wsb + 2 * MB);
    ushort_t* vhi = (ushort_t*)(wsb + 4 * MB);
    ushort_t* vlo = (ushort_t*)(wsb + 6 * MB);
    unsigned* mw  = (unsigned*)(wsb + 8 * MB);

    prep<<<dim3(1024), 256, 0, stream>>>(k, v, mask, khi, klo, vhi, vlo, mw);
    fused_qk_conv_av<<<dim3(NSB, NBH), 512, 0, stream>>>(
        q, khi, klo, mw, vhi, vlo, conv_w, conv_b, lin_w, lin_b, out);
}

// Round 20
// 121.638 us; speedup vs baseline: 1.1570x; 1.0804x over previous
//
#include <hip/hip_runtime.h>
#include <math.h>

#define S_LEN 1024
#define D_DIM 64
#define NBH   16
#define RPB   14
#define NSB   74           // ceil(1024/14)

typedef unsigned short ushort_t;
typedef unsigned int uint_t;
typedef __attribute__((ext_vector_type(8))) _Float16 half8;  // 8 f16 (4 VGPRs)
typedef __attribute__((ext_vector_type(2))) _Float16 h2;
typedef __attribute__((ext_vector_type(4))) short short4v;   // 8 B
typedef __attribute__((ext_vector_type(4))) float f32x4;
typedef __attribute__((ext_vector_type(2))) float f32x2;

__device__ __forceinline__ ushort_t f16bits(float x) {
    _Float16 h = (_Float16)x;                 // RNE
    ushort_t b;
    __builtin_memcpy(&b, &h, 2);
    return b;
}
__device__ __forceinline__ h2 as_h2(uint_t u) {
    h2 r;
    __builtin_memcpy(&r, &u, 4);
    return r;
}

// ------------------------------ Prep ----------------------------------------
// blocks [0,512):    K -> f16 QK B-frag tiled layout (16B stores)
// blocks [512,768):  V transpose -> f16 PV B-frag tiled layout
// blocks [768,1024): mask bit-pack, thread-per-word
__global__ __launch_bounds__(256) void prep(
    const float* __restrict__ k, const float* __restrict__ v,
    const int* __restrict__ mask,
    ushort_t* __restrict__ kh, ushort_t* __restrict__ vh,
    unsigned* __restrict__ mw)
{
    __shared__ float Ls[64][65];
    const int tid = threadIdx.x;
    const int bx = blockIdx.x;
    if (bx < 512) {
        const int gid  = bx * 256 + tid;          // 0..131071
        const int bh   = gid >> 13;
        const int tile = (gid >> 7) & 63;
        const int ch   = (gid >> 6) & 1;
        const int lane = gid & 63;
        const int quad = lane >> 4, t15 = lane & 15;
        const float* src = k + ((size_t)bh * S_LEN + tile * 16 + t15) * D_DIM
                             + ch * 32 + quad * 8;
        float x[8];
        *(float4*)(x + 0) = *(const float4*)(src);
        *(float4*)(x + 4) = *(const float4*)(src + 4);
        ushort_t hv[8];
        #pragma unroll
        for (int i = 0; i < 8; ++i) hv[i] = f16bits(x[i]);
        *(short4v*)(kh + (size_t)gid * 8)     = *(short4v*)(hv);
        *(short4v*)(kh + (size_t)gid * 8 + 4) = *(short4v*)(hv + 4);
    } else if (bx < 768) {
        const int bi = bx - 512;
        const int tt = bi & 15, bh = bi >> 4;
        const float* vb = v + ((size_t)bh * S_LEN + tt * 64) * D_DIM;
        #pragma unroll
        for (int p = 0; p < 4; ++p) {
            int idx = p * 1024 + tid * 4;
            int r = idx >> 6, c = idx & 63;
            float4 x = *(const float4*)(vb + r * 64 + c);
            Ls[r][c] = x.x; Ls[r][c+1] = x.y; Ls[r][c+2] = x.z; Ls[r][c+3] = x.w;
        }
        __syncthreads();
        const int d = tid >> 2, c0 = (tid & 3) * 16;
        ushort_t hi[16];
        #pragma unroll
        for (int j = 0; j < 16; ++j) hi[j] = f16bits(Ls[c0 + j][d]);
        const int tb0 = tt * 8 + (c0 >> 3);
        const size_t o0 = (((size_t)bh * 128 + tb0) * 64 + d) * 8;
        const size_t o1 = (((size_t)bh * 128 + tb0 + 1) * 64 + d) * 8;
        *(short4v*)(vh + o0)     = *(short4v*)(hi);
        *(short4v*)(vh + o0 + 4) = *(short4v*)(hi + 4);
        *(short4v*)(vh + o1)     = *(short4v*)(hi + 8);
        *(short4v*)(vh + o1 + 4) = *(short4v*)(hi + 12);
    } else {
        const int gid = (bx - 768) * 256 + tid;    // 0..65535
        const int row = gid >> 5, wd = gid & 31;   // row = b*1024+s
        const int4* mp = (const int4*)(mask + (size_t)row * 1024 + wd * 32);
        unsigned bits = 0;
        #pragma unroll
        for (int p = 0; p < 8; ++p) {
            int4 qv = mp[p];
            bits |= (qv.x != 0 ? 1u : 0u) << (p * 4 + 0);
            bits |= (qv.y != 0 ? 1u : 0u) << (p * 4 + 1);
            bits |= (qv.z != 0 ? 1u : 0u) << (p * 4 + 2);
            bits |= (qv.w != 0 ? 1u : 0u) << (p * 4 + 3);
        }
        mw[(size_t)row * 32 + wd] = bits;
    }
}

// ---------- Fused (RPB=14, f16): QK^T (LDS f16) -> conv+mask+exp -> PV -------
// grid (74 s-tiles, 16 bh), block 512 = 8 waves. LDS ~73.5 KB -> 2 blocks/CU.
// Phase A: ONE 16-row f16 A-set (rows s0-1+m, pre-scaled 1/8); per K-tile
//          2 chained f16 MFMAs. dpH layout: col t at idx t+2 (pads 0,1 and
//          1026,1027 zeroed) so conv windows are two aligned b64 reads.
// Phase B: fp32 conv core; P -> f16 in LDS.
// Phase C: PV single-f16 MFMA per chunk; 1/rowsum in epilogue.
#define DPSTR 1040  // dp row stride (halfs)
#define PSTR  1048  // pP row stride (halfs)
__global__ __launch_bounds__(512) void fused_qk_conv_av(
    const float* __restrict__ q,
    const ushort_t* __restrict__ kh, const unsigned* __restrict__ mw,
    const ushort_t* __restrict__ vh,
    const float* __restrict__ conv_w, const float* __restrict__ conv_b,
    const float* __restrict__ lin_w, const float* __restrict__ lin_b,
    float* __restrict__ out)
{
    __shared__ ushort_t dpH[16 * DPSTR];   // 33.3 KB f16 dp rows s0-1..s0+14
    __shared__ ushort_t pP[16 * PSTR];     // 33.5 KB f16 P
    __shared__ float oBuf[16][68];         // 4.4 KB
    __shared__ float lsPart[16][4];
    __shared__ unsigned mb[16][32];        // 2 KB

    const int st = blockIdx.x, bh = blockIdx.y;
    const int s0 = st * RPB;
    const int b  = bh >> 3;
    const int tid = threadIdx.x;
    const int wave = tid >> 6, lane = tid & 63;
    const int m = lane & 15, quad = lane >> 4;

    // mask bits -> LDS (one word per thread; row o <-> s = s0-1+o)
    {
        const int o = tid >> 5, wd = tid & 31;
        const int s = s0 - 1 + o;
        mb[o][wd] = (s >= 0 && s < S_LEN)
                  ? mw[((size_t)b * S_LEN + s) * 32 + wd] : 0u;
    }
    // zero dpH pads: idx 0,1 (t=-2,-1) and 1026,1027 (t=1024,1025) per row
    if (tid < 64) {
        const int row = tid >> 2, i = tid & 3;
        const int idx = (i < 2) ? i : 1024 + i;
        dpH[row * DPSTR + idx] = 0;
    }

    // ---------------- Phase A: QK into LDS (single f16 A-set) ---------------
    const int sA = s0 - 1 + m;
    const int sQ = sA < 0 ? 0 : (sA > S_LEN - 1 ? S_LEN - 1 : sA);
    const float* qp = q + ((size_t)bh * S_LEN + sQ) * D_DIM + quad * 8;
    float qa[16];
    *(float4*)(qa + 0)  = *(const float4*)(qp + 0);
    *(float4*)(qa + 4)  = *(const float4*)(qp + 4);
    *(float4*)(qa + 8)  = *(const float4*)(qp + 32);
    *(float4*)(qa + 12) = *(const float4*)(qp + 36);
    half8 AH0, AH1;
    #pragma unroll
    for (int i = 0; i < 8; ++i) {
        AH0[i] = (_Float16)(qa[i] * 0.125f);
        AH1[i] = (_Float16)(qa[8 + i] * 0.125f);
    }

    #pragma unroll
    for (int tt = 0; tt < 8; ++tt) {
        const int tile = wave * 8 + tt;
        const size_t kb = (((size_t)bh * 64 + tile) * 128 + lane) * 8;
        half8 KH0 = *(const half8*)(kh + kb);
        half8 KH1 = *(const half8*)(kh + kb + 512);
        f32x4 a = {0.f, 0.f, 0.f, 0.f};
        a = __builtin_amdgcn_mfma_f32_16x16x32_f16(AH0, KH0, a, 0, 0, 0);
        a = __builtin_amdgcn_mfma_f32_16x16x32_f16(AH1, KH1, a, 0, 0, 0);
        const int col = tile * 16 + m;
        #pragma unroll
        for (int r = 0; r < 4; ++r) {
            const int row = quad * 4 + r;
            const int s = s0 - 1 + row;
            const float v = (s >= 0 && s < S_LEN) ? a[r] : 0.f;
            dpH[row * DPSTR + col + 2] = f16bits(v);
        }
    }

    float w[36];
    #pragma unroll
    for (int i = 0; i < 36; ++i) w[i] = conv_w[i];
    float cb[4], lw[4];
    #pragma unroll
    for (int f = 0; f < 4; ++f) { cb[f] = conv_b[f]; lw[f] = lin_w[f]; }
    const float lb = lin_b[0];
    const f32x2 zero2 = {0.f, 0.f};
    const f32x2 c001  = {0.01f, 0.01f};

    __syncthreads();

    // ---------------- Phase B: conv + mask + exp -----------------------------
    const int rh = tid >> 8, cg = tid & 255, c0 = cg * 4;
    #pragma unroll
    for (int pass = 0; pass < 2; ++pass) {
        const int obase = rh * 8 + pass * 4;        // first of 4 output rows
        // 6-row window from LDS: two aligned b64 reads per row (halo-padded)
        float rowv[6][6];
        #pragma unroll
        for (int jj = 0; jj < 6; ++jj) {
            const int dr = obase - 1 + jj;          // -1..16
            if (dr >= 0 && dr < 16) {
                const ushort_t* rp = &dpH[dr * DPSTR + c0];
                uint2 r0 = *(const uint2*)rp;        // t: c0-2,c0-1 | c0,c0+1
                uint2 r1 = *(const uint2*)(rp + 4);  // t: c0+2,c0+3 | c0+4,c0+5
                h2 pA = as_h2(r0.x), pB = as_h2(r0.y);
                h2 pC = as_h2(r1.x), pD = as_h2(r1.y);
                rowv[jj][0] = (float)pA[1];
                rowv[jj][1] = (float)pB[0]; rowv[jj][2] = (float)pB[1];
                rowv[jj][3] = (float)pC[0]; rowv[jj][4] = (float)pC[1];
                rowv[jj][5] = (float)pD[0];
            } else {
                #pragma unroll
                for (int i = 0; i < 6; ++i) rowv[jj][i] = 0.f;
            }
        }
        float ls[4];
        #pragma unroll
        for (int jo = 0; jo < 4; ++jo) {
            const int o = obase + jo;
            const bool act = (o >= 1) && (o <= RPB) && (s0 - 1 + o < S_LEN);
            if (act) {
                f32x2 pa = {lb, lb}, pb = {lb, lb};
                #pragma unroll
                for (int f = 0; f < 4; ++f) {
                    f32x2 ca = {cb[f], cb[f]}, cbv = ca;
                    #pragma unroll
                    for (int dr = 0; dr < 3; ++dr) {
                        const float* vv = rowv[jo + dr];
                        #pragma unroll
                        for (int dc = 0; dc < 3; ++dc) {
                            const float wt = w[f * 9 + dr * 3 + dc];
                            const f32x2 wt2 = {wt, wt};
                            f32x2 ia = {vv[dc],     vv[dc + 1]};
                            f32x2 ib = {vv[dc + 2], vv[dc + 3]};
                            ca  = __builtin_elementwise_fma(wt2, ia, ca);
                            cbv = __builtin_elementwise_fma(wt2, ib, cbv);
                        }
                    }
                    const f32x2 lwv = {lw[f], lw[f]};
                    f32x2 la  = __builtin_elementwise_fma(
                        c001, __builtin_elementwise_min(ca, zero2),
                        __builtin_elementwise_max(ca, zero2));
                    f32x2 lb2 = __builtin_elementwise_fma(
                        c001, __builtin_elementwise_min(cbv, zero2),
                        __builtin_elementwise_max(cbv, zero2));
                    pa = __builtin_elementwise_fma(lwv, la, pa);
                    pb = __builtin_elementwise_fma(lwv, lb2, pb);
                }
                const unsigned word = mb[o][cg >> 3];
                const unsigned nib  = (word >> ((cg & 7) * 4)) & 0xFu;
                float pre[4] = {pa.x, pa.y, pb.x, pb.y};
                #pragma unroll
                for (int i = 0; i < 4; ++i)
                    if (!((nib >> i) & 1u)) pre[i] = -1e30f;
                float pv[4];
                #pragma unroll
                for (int i = 0; i < 4; ++i) pv[i] = __expf(pre[i]);
                ls[jo] = (pv[0] + pv[1]) + (pv[2] + pv[3]);
                uint2 hv;
                hv.x = (uint_t)f16bits(pv[0]) | ((uint_t)f16bits(pv[1]) << 16);
                hv.y = (uint_t)f16bits(pv[2]) | ((uint_t)f16bits(pv[3]) << 16);
                *(uint2*)&pP[o * PSTR + c0] = hv;
            } else {
                uint2 z = {0u, 0u};
                *(uint2*)&pP[o * PSTR + c0] = z;
                ls[jo] = 0.f;
            }
        }
        #pragma unroll
        for (int jo = 0; jo < 4; ++jo) {
            float t = ls[jo];
            #pragma unroll
            for (int off = 1; off < 64; off <<= 1) t += __shfl_xor(t, off);
            if (lane == 0) lsPart[obase + jo][wave & 3] = t;
        }
    }
    __syncthreads();

    // ---------------- Phase C: PV (single f16 MFMA per chunk) ---------------
    const int d0 = (wave & 3) * 16;
    const int th = wave >> 2;
    f32x4 O = {0.f, 0.f, 0.f, 0.f};
    #pragma unroll 4
    for (int i = 0; i < 16; ++i) {
        const int c = th * 16 + i;
        half8 ph = *(const half8*)&pP[m * PSTR + c * 32 + quad * 8];
        const size_t vb = (((size_t)bh * 128 + c * 4 + quad) * 64 + d0 + m) * 8;
        half8 vv = *(const half8*)(vh + vb);
        O = __builtin_amdgcn_mfma_f32_16x16x32_f16(ph, vv, O, 0, 0, 0);
    }
    if (wave < 4) {
        #pragma unroll
        for (int r = 0; r < 4; ++r) oBuf[quad * 4 + r][d0 + m] = O[r];
    }
    __syncthreads();
    if (wave >= 4) {
        #pragma unroll
        for (int r = 0; r < 4; ++r) {
            const int br = quad * 4 + r;
            const int s = s0 - 1 + br;
            if (br >= 1 && br <= RPB && s < S_LEN) {
                const float lsum = (lsPart[br][0] + lsPart[br][1]) +
                                   (lsPart[br][2] + lsPart[br][3]);
                out[((size_t)bh * S_LEN + s) * D_DIM + d0 + m] =
                    (O[r] + oBuf[br][d0 + m]) / lsum;
            }
        }
    }
}

extern "C" void kernel_launch(void* const* d_in, const int* in_sizes, int n_in,
                              void* d_out, int out_size, void* d_ws, size_t ws_size,
                              hipStream_t stream) {
    const float* q      = (const float*)d_in[0];
    const float* k      = (const float*)d_in[1];
    const float* v      = (const float*)d_in[2];
    const int*   mask   = (const int*)d_in[3];
    const float* conv_w = (const float*)d_in[4];
    const float* conv_b = (const float*)d_in[5];
    const float* lin_w  = (const float*)d_in[6];
    const float* lin_b  = (const float*)d_in[7];
    float* out = (float*)d_out;

    char* wsb = (char*)d_ws;
    const size_t MB = 1024 * 1024;
    ushort_t* kh = (ushort_t*)(wsb + 0 * MB);     // 2 MiB
    ushort_t* vh = (ushort_t*)(wsb + 2 * MB);     // 2 MiB
    unsigned* mw = (unsigned*)(wsb + 4 * MB);     // 256 KiB

    prep<<<dim3(1024), 256, 0, stream>>>(k, v, mask, kh, vh, mw);
    fused_qk_conv_av<<<dim3(NSB, NBH), 512, 0, stream>>>(
        q, kh, mw, vh, conv_w, conv_b, lin_w, lin_b, out);
}